// Round 6
// baseline (71549.908 us; speedup 1.0000x reference)
//
#include <hip/hip_runtime.h>
#include <hip/hip_bf16.h>
#include <cmath>

using bf16 = __hip_bfloat16;

__device__ __forceinline__ float b2f(bf16 v) { return __bfloat162float(v); }

// ---- dtype detection: flag=1 -> inputs are f32, flag=0 -> inputs are bf16 --
__global__ void detect_dtype(const unsigned short* x, int* flag) {
    __shared__ int cnt[256];
    int t = threadIdx.x, bad = 0;
    for (int i = t; i < 8192; i += 256) {
        unsigned short lo = x[2 * i];
        int e = (lo >> 7) & 0xFF;
        if (e == 0xFF || e >= 0xC6 || (e != 0 && e <= 0x30)) bad++;
    }
    cnt[t] = bad; __syncthreads();
    if (t == 0) { int s = 0; for (int i = 0; i < 256; i++) s += cnt[i]; *flag = (s > 819) ? 1 : 0; }
}

__device__ __forceinline__ float rd(const void* src, long i, int f) {
    return f ? ((const float*)src)[i] : b2f(((const bf16*)src)[i]);
}

// raw (flag-dtype) -> f32 scratch
__global__ void cvt_f32(const void* __restrict__ src, long eoff, float* __restrict__ dst,
                        long n, const int* __restrict__ flag) {
    int f = *flag;
    long i = (long)blockIdx.x * 256 + threadIdx.x;
    if (i < n) dst[i] = rd(src, eoff + i, f);
}

// LayerNorm over D=768. srcraw=1: src is raw flag-dtype; srcraw=0: src is bf16 buffer.
__global__ __launch_bounds__(256) void ln_gen(const void* __restrict__ src, int srcraw,
                                              const void* __restrict__ gw,
                                              const void* __restrict__ bw,
                                              float* __restrict__ dst, long row0,
                                              const int* __restrict__ flag)
{
    const int fl = *flag;
    const long gr = row0 + blockIdx.x;
    const int t = threadIdx.x;
    float v[3], s = 0.f, s2 = 0.f;
#pragma unroll
    for (int i = 0; i < 3; i++) {
        long gi = gr * 768 + t + 256 * i;
        float f0 = srcraw ? rd(src, gi, fl) : b2f(((const bf16*)src)[gi]);
        v[i] = f0; s += f0; s2 += f0 * f0;
    }
#pragma unroll
    for (int o = 32; o; o >>= 1) { s += __shfl_xor(s, o); s2 += __shfl_xor(s2, o); }
    __shared__ float a1[4], a2[4];
    if ((t & 63) == 0) { a1[t >> 6] = s; a2[t >> 6] = s2; }
    __syncthreads();
    s = a1[0] + a1[1] + a1[2] + a1[3];
    s2 = a2[0] + a2[1] + a2[2] + a2[3];
    float mu = s * (1.f / 768.f);
    float var = s2 * (1.f / 768.f) - mu * mu;
    float rstd = rsqrtf(var + 1e-5f);
#pragma unroll
    for (int i = 0; i < 3; i++) {
        int c = t + 256 * i;
        dst[(long)blockIdx.x * 768 + c] = (v[i] - mu) * rstd * rd(gw, c, fl) + rd(bw, c, fl);
    }
}

// softmax over 197 fp32 scores -> fp32 attn, 4 rows/block (1 wave each)
__global__ __launch_bounds__(256) void softmax_rows(const float* __restrict__ sc,
                                                    float* __restrict__ attn, long nrows)
{
    const long row = (long)blockIdx.x * 4 + (threadIdx.x >> 6);
    if (row >= nrows) return;
    const int lane = threadIdx.x & 63;
    const float* sr = sc + row * 197;
    float v[4], mx = -1e30f;
#pragma unroll
    for (int j = 0; j < 4; j++) {
        int s = lane + j * 64;
        float f = (s < 197) ? sr[s] : -1e30f;
        v[j] = f; mx = fmaxf(mx, f);
    }
#pragma unroll
    for (int o = 32; o; o >>= 1) mx = fmaxf(mx, __shfl_xor(mx, o));
    float sum = 0.f;
#pragma unroll
    for (int j = 0; j < 4; j++) {
        int s = lane + j * 64;
        float e = (s < 197) ? __expf(v[j] - mx) : 0.f;
        v[j] = e; sum += e;
    }
#pragma unroll
    for (int o = 32; o; o >>= 1) sum += __shfl_xor(sum, o);
    float inv = 1.f / sum;
    float* ar = attn + row * 197;
#pragma unroll
    for (int j = 0; j < 4; j++) {
        int s = lane + j * 64;
        if (s < 197) ar[s] = v[j] * inv;
    }
}

// ---------------------------------------------------------------------------
// Naive C = A @ B^T, one wave per output element. A:[M,lda] f32, B:[N,ldb] f32.
// Lanes stride K; float4 fast path over 256-elem blocks; shuffle reduction.
// Batched via blockIdx.y (strides sA/sB).
// MODE 0: C f32 [m*N+n] = (acc + raw1[r1off+n]) * scale        (q/k proj)
// MODE 1: C f32 vT[((m/197)*768+n)*197 + m%197] = acc + raw1[r1off+n]
// MODE 2: C f32 [bz*38809 + m*197 + n] = acc                   (scores)
// MODE 3: C f32 aoT[(bz*768+n)*2364 + hoff + m] = acc          (AV)
// MODE 4: C bf16 outS[gi] = acc + raw1[m] + raw2[gi], gi=(row0+bz*197+m)*768+n
// MODE 5: C f32 [m*N+n] = gelu(acc + raw1[n])                  (mlp1)
// MODE 6: d_out[(row0+m)*768+n] = acc + raw1[n] + raw2f32[m*768+n], dtype=flag
// ---------------------------------------------------------------------------
template <int MODE>
__global__ __launch_bounds__(256) void ngemm(
    const float* __restrict__ A, const float* __restrict__ B, void* __restrict__ C,
    const void* __restrict__ raw1, long r1off, const void* __restrict__ raw2,
    int M, int N, int K, int lda, int ldb, long sA, long sB,
    int hoff, long row0, float scale, const int* __restrict__ flag)
{
    const int wave = threadIdx.x >> 6, lane = threadIdx.x & 63;
    const long idx = (long)blockIdx.x * 4 + wave;
    if (idx >= (long)M * N) return;
    const int bz = blockIdx.y;
    const int m = (int)(idx / N), n = (int)(idx - (long)m * N);
    const float* Ar = A + (long)bz * sA + (long)m * lda;
    const float* Br = B + (long)bz * sB + (long)n * ldb;
    float acc = 0.f;
    const int k4 = K & ~255;
    for (int k0 = 0; k0 < k4; k0 += 256) {
        const float4 a = *(const float4*)(Ar + k0 + lane * 4);
        const float4 b = *(const float4*)(Br + k0 + lane * 4);
        acc += a.x * b.x + a.y * b.y + a.z * b.z + a.w * b.w;
    }
    for (int k = k4 + lane; k < K; k += 64) acc += Ar[k] * Br[k];
#pragma unroll
    for (int o = 32; o; o >>= 1) acc += __shfl_xor(acc, o);
    if (lane != 0) return;
    const int fl = *flag;
    if constexpr (MODE == 0) {
        ((float*)C)[(long)m * N + n] = (acc + rd(raw1, r1off + n, fl)) * scale;
    } else if constexpr (MODE == 1) {
        int b_ = m / 197, t = m - b_ * 197;
        ((float*)C)[((long)b_ * 768 + n) * 197 + t] = acc + rd(raw1, r1off + n, fl);
    } else if constexpr (MODE == 2) {
        ((float*)C)[(long)bz * 38809 + (long)m * 197 + n] = acc;
    } else if constexpr (MODE == 3) {
        ((float*)C)[((long)bz * 768 + n) * 2364 + hoff + m] = acc;
    } else if constexpr (MODE == 4) {
        long gi = (row0 + (long)bz * 197 + m) * 768 + n;
        ((bf16*)C)[gi] = __float2bfloat16(acc + rd(raw1, m, fl) + rd(raw2, gi, fl));
    } else if constexpr (MODE == 5) {
        float xv = acc + rd(raw1, r1off + n, fl);
        xv = 0.5f * xv * (1.f + erff(xv * 0.70710678f));
        ((float*)C)[(long)m * N + n] = xv;
    } else if constexpr (MODE == 6) {
        float res = acc + rd(raw1, r1off + n, fl) + ((const float*)raw2)[(long)m * 768 + n];
        long ad = (row0 + m) * 768 + n;
        if (fl) ((float*)C)[ad] = res;
        else    ((bf16*)C)[ad] = __float2bfloat16(res);
    }
}

extern "C" void kernel_launch(void* const* d_in, const int* in_sizes, int n_in,
                              void* d_out, int out_size, void* d_ws, size_t ws_size,
                              hipStream_t stream)
{
    const void* x    = d_in[0];
    const void* ln1g = d_in[1];
    const void* ln1b = d_in[2];
    const void* Wq   = d_in[3];
    const void* bq   = d_in[4];
    const void* Wk   = d_in[5];
    const void* bk   = d_in[6];
    const void* Wv   = d_in[7];
    const void* bv   = d_in[8];
    const void* Wmap = d_in[9];
    const void* bmap = d_in[10];
    const void* ln2g = d_in[11];
    const void* ln2b = d_in[12];
    const void* W1   = d_in[13];
    const void* b1   = d_in[14];
    const void* W2   = d_in[15];
    const void* b2   = d_in[16];
    (void)in_sizes; (void)n_in; (void)out_size;

    auto al   = [](size_t v) { return (v + 255) & ~(size_t)255; };
    auto cdiv = [](long a, long b) { return (int)((a + b - 1) / b); };

    // ---- reserved (lives across both phases) ----
    char* W = (char*)d_ws;
    size_t o = 0;
    auto take = [&](size_t bytes) -> char* { char* p = W + o; o += al(bytes); return p; };
    int*  flag = (int*)take(256);
    bf16* outS = (bf16*)take(6304ull * 768 * 2);   // x + msa, bf16 staging
    const size_t reservedB = o;
    char* arena = W + reservedB;

    // ---- adaptive chunk sizes ----
    auto p1need = [&](int BC) -> size_t {
        size_t b = (size_t)BC;
        return reservedB + al(465708ull * 4) + al(589824ull * 4)
             + 4 * al(b * 605184)            // hlnC, qC, kC, vTC
             + 2 * al(b * 155236)            // scores, attn
             + al(b * 7262208);              // aoT
    };
    int BC = 1;
    { const int ch[4] = {8, 4, 2, 1};
      for (int i = 0; i < 4; i++) if (p1need(ch[i]) <= ws_size) { BC = ch[i]; break; } }

    auto p2need = [&](int MC) -> size_t {
        return reservedB + 2 * al(9437184ull)
             + al((size_t)MC * 768 * 4) + al((size_t)MC * 3072 * 4);
    };
    int MC = 197;
    { const int ch[5] = {3152, 1576, 788, 394, 197};
      for (int i = 0; i < 5; i++) if (p2need(ch[i]) <= ws_size) { MC = ch[i]; break; } }

    // phase-1 buffers
    size_t po = 0;
    auto ptake = [&](size_t bytes) -> char* { char* p = arena + po; po += al(bytes); return p; };
    float* wmapF   = (float*)ptake(465708ull * 4);
    float* wF      = (float*)ptake(589824ull * 4);
    float* hlnC    = (float*)ptake((size_t)BC * 605184);
    float* qC      = (float*)ptake((size_t)BC * 605184);
    float* kC      = (float*)ptake((size_t)BC * 605184);
    float* vTC     = (float*)ptake((size_t)BC * 605184);
    float* scoresC = (float*)ptake((size_t)BC * 155236);
    float* attnC   = (float*)ptake((size_t)BC * 155236);
    float* aoTC    = (float*)ptake((size_t)BC * 7262208);
    // phase-2 buffers (alias arena; phase-1 data dead by then)
    size_t qo = 0;
    auto qtake = [&](size_t bytes) -> char* { char* p = arena + qo; qo += al(bytes); return p; };
    float* W1F = (float*)qtake(9437184ull);
    float* W2F = (float*)qtake(9437184ull);
    float* h2C = (float*)qtake((size_t)MC * 768 * 4);
    float* gC  = (float*)qtake((size_t)MC * 3072 * 4);

    detect_dtype<<<1, 256, 0, stream>>>((const unsigned short*)x, flag);
    cvt_f32<<<cdiv(465708, 256), 256, 0, stream>>>(Wmap, 0, wmapF, 465708, flag);

    const int Mr = BC * 197;
    for (int c0 = 0; c0 < 32; c0 += BC) {
        const long row0 = (long)c0 * 197;
        ln_gen<<<Mr, 256, 0, stream>>>(x, 1, ln1g, ln1b, hlnC, row0, flag);
        for (int h = 0; h < 12; h++) {
            const long woff = (long)h * 589824;
            // q
            cvt_f32<<<2304, 256, 0, stream>>>(Wq, woff, wF, 589824, flag);
            ngemm<0><<<dim3(cdiv((long)Mr * 768, 4), 1), 256, 0, stream>>>(
                hlnC, wF, qC, bq, (long)h * 768, nullptr,
                Mr, 768, 768, 768, 768, 0, 0, 0, 0, 1.0f / 14.0f, flag);
            // k
            cvt_f32<<<2304, 256, 0, stream>>>(Wk, woff, wF, 589824, flag);
            ngemm<0><<<dim3(cdiv((long)Mr * 768, 4), 1), 256, 0, stream>>>(
                hlnC, wF, kC, bk, (long)h * 768, nullptr,
                Mr, 768, 768, 768, 768, 0, 0, 0, 0, 1.0f, flag);
            // v -> vT
            cvt_f32<<<2304, 256, 0, stream>>>(Wv, woff, wF, 589824, flag);
            ngemm<1><<<dim3(cdiv((long)Mr * 768, 4), 1), 256, 0, stream>>>(
                hlnC, wF, vTC, bv, (long)h * 768, nullptr,
                Mr, 768, 768, 768, 768, 0, 0, 0, 0, 1.0f, flag);
            // scores = q @ k^T (per batch)
            ngemm<2><<<dim3(cdiv(197L * 197, 4), BC), 256, 0, stream>>>(
                qC, kC, scoresC, nullptr, 0, nullptr,
                197, 197, 768, 768, 768, 197L * 768, 197L * 768, 0, 0, 1.0f, flag);
            softmax_rows<<<cdiv((long)BC * 197, 4), 256, 0, stream>>>(scoresC, attnC, (long)BC * 197);
            // ao = attn @ vT^T -> aoT slice
            ngemm<3><<<dim3(cdiv(197L * 768, 4), BC), 256, 0, stream>>>(
                attnC, vTC, aoTC, nullptr, 0, nullptr,
                197, 768, 197, 197, 197, 38809L, 768L * 197, h * 197, 0, 1.0f, flag);
        }
        // msa + bmap + x -> outS (bf16), K = 2364 over all heads
        ngemm<4><<<dim3(cdiv(197L * 768, 4), BC), 256, 0, stream>>>(
            wmapF, aoTC, outS, bmap, 0, x,
            197, 768, 2364, 2364, 2364, 0, 768L * 2364, 0, row0, 1.0f, flag);
    }

    // ---- MLP phase ----
    cvt_f32<<<9216, 256, 0, stream>>>(W1, 0, W1F, 2359296, flag);
    cvt_f32<<<9216, 256, 0, stream>>>(W2, 0, W2F, 2359296, flag);
    for (int r0 = 0; r0 < 6304; r0 += MC) {
        ln_gen<<<MC, 256, 0, stream>>>(outS, 0, ln2g, ln2b, h2C, r0, flag);
        ngemm<5><<<dim3(cdiv((long)MC * 3072, 4), 1), 256, 0, stream>>>(
            h2C, W1F, gC, b1, 0, nullptr,
            MC, 3072, 768, 768, 768, 0, 0, 0, 0, 1.0f, flag);
        ngemm<6><<<dim3(cdiv((long)MC * 768, 4), 1), 256, 0, stream>>>(
            gC, W2F, d_out, b2, 0, h2C,
            MC, 768, 3072, 3072, 3072, 0, 0, 0, r0, 1.0f, flag);
    }
}

// Round 7
// 2437.398 us; speedup vs baseline: 29.3550x; 29.3550x over previous
//
#include <hip/hip_runtime.h>
#include <hip/hip_bf16.h>
#include <cmath>

using bf16 = __hip_bfloat16;
typedef __bf16 bfx8 __attribute__((ext_vector_type(8)));
typedef float floatx4 __attribute__((ext_vector_type(4)));

__device__ __forceinline__ float b2f(bf16 v) { return __bfloat162float(v); }

// ---- dtype detection: flag=1 -> inputs are f32, flag=0 -> inputs are bf16 --
__global__ void detect_dtype(const unsigned short* x, int* flag) {
    __shared__ int cnt[256];
    int t = threadIdx.x, bad = 0;
    for (int i = t; i < 8192; i += 256) {
        unsigned short lo = x[2 * i];
        int e = (lo >> 7) & 0xFF;
        if (e == 0xFF || e >= 0xC6 || (e != 0 && e <= 0x30)) bad++;
    }
    cnt[t] = bad; __syncthreads();
    if (t == 0) { int s = 0; for (int i = 0; i < 256; i++) s += cnt[i]; *flag = (s > 819) ? 1 : 0; }
}

__device__ __forceinline__ float rd(const void* src, long i, int f) {
    return f ? ((const float*)src)[i] : b2f(((const bf16*)src)[i]);
}

// raw (flag-dtype) -> bf16 scratch
__global__ void cvt_b16(const void* __restrict__ src, bf16* __restrict__ dst,
                        long n, const int* __restrict__ flag) {
    int f = *flag;
    long i = (long)blockIdx.x * 256 + threadIdx.x;
    if (i < n) dst[i] = __float2bfloat16(rd(src, i, f));
}

// fused Wq/Wk/Wv head-slice convert into combined [3*768*768] bf16
__global__ void cvt3(const void* a, const void* b, const void* c, long eoff,
                     bf16* dst, const int* flag) {
    int f = *flag; const long n = 589824;   // 768*768
    long i = (long)blockIdx.x * 256 + threadIdx.x;
    if (i >= n) return;
    dst[i]         = __float2bfloat16(rd(a, eoff + i, f));
    dst[n + i]     = __float2bfloat16(rd(b, eoff + i, f));
    dst[2 * n + i] = __float2bfloat16(rd(c, eoff + i, f));
}

// Wmap [197,2364] -> bf16 padded [197, 12*224], zeros in pad columns
__global__ void pad_wmap(const void* wm, bf16* wp, const int* flag) {
    int f = *flag;
    int idx = blockIdx.x * 256 + threadIdx.x;   // 197*2688
    if (idx >= 197 * 2688) return;
    int t = idx / 2688, c = idx - t * 2688;
    int h = c / 224, j = c - h * 224;
    wp[idx] = __float2bfloat16(j < 197 ? rd(wm, (long)t * 2364 + h * 197 + j, f) : 0.f);
}

// LayerNorm over D=768 -> bf16. srcraw=1: src raw flag-dtype; 0: src bf16 buf.
__global__ __launch_bounds__(256) void ln_bf(const void* __restrict__ src, int srcraw,
                                             const void* __restrict__ gw,
                                             const void* __restrict__ bw,
                                             bf16* __restrict__ dst, long row0,
                                             const int* __restrict__ flag)
{
    const int fl = *flag;
    const long gr = row0 + blockIdx.x;
    const int t = threadIdx.x;
    float v[3], s = 0.f, s2 = 0.f;
#pragma unroll
    for (int i = 0; i < 3; i++) {
        long gi = gr * 768 + t + 256 * i;
        float f0 = srcraw ? rd(src, gi, fl) : b2f(((const bf16*)src)[gi]);
        v[i] = f0; s += f0; s2 += f0 * f0;
    }
#pragma unroll
    for (int o = 32; o; o >>= 1) { s += __shfl_xor(s, o); s2 += __shfl_xor(s2, o); }
    __shared__ float a1[4], a2[4];
    if ((t & 63) == 0) { a1[t >> 6] = s; a2[t >> 6] = s2; }
    __syncthreads();
    s = a1[0] + a1[1] + a1[2] + a1[3];
    s2 = a2[0] + a2[1] + a2[2] + a2[3];
    float mu = s * (1.f / 768.f);
    float var = s2 * (1.f / 768.f) - mu * mu;
    float rstd = rsqrtf(var + 1e-5f);
#pragma unroll
    for (int i = 0; i < 3; i++) {
        int c = t + 256 * i;
        dst[(long)blockIdx.x * 768 + c] =
            __float2bfloat16((v[i] - mu) * rstd * rd(gw, c, fl) + rd(bw, c, fl));
    }
}

// softmax over 197 fp32 scores -> bf16 rows padded to 224 with zeros
__global__ __launch_bounds__(256) void softmax_rows(const float* __restrict__ sc,
                                                    bf16* __restrict__ attn, long nrows)
{
    const long row = (long)blockIdx.x * 4 + (threadIdx.x >> 6);
    if (row >= nrows) return;
    const int lane = threadIdx.x & 63;
    const float* sr = sc + row * 197;
    float v[4], mx = -1e30f;
#pragma unroll
    for (int j = 0; j < 4; j++) {
        int s = lane + j * 64;
        float f = (s < 197) ? sr[s] : -1e30f;
        v[j] = f; mx = fmaxf(mx, f);
    }
#pragma unroll
    for (int o = 32; o; o >>= 1) mx = fmaxf(mx, __shfl_xor(mx, o));
    float sum = 0.f;
#pragma unroll
    for (int j = 0; j < 4; j++) {
        int s = lane + j * 64;
        float e = (s < 197) ? __expf(v[j] - mx) : 0.f;
        v[j] = e; sum += e;
    }
#pragma unroll
    for (int o = 32; o; o >>= 1) sum += __shfl_xor(sum, o);
    float inv = 1.f / sum;
    bf16* ar = attn + row * 224;
#pragma unroll
    for (int j = 0; j < 4; j++) {
        int s = lane + j * 64;
        if (s < 224) ar[s] = __float2bfloat16((s < 197) ? v[j] * inv : 0.f);
    }
}

// ---------------------------------------------------------------------------
// MFMA C = A @ B^T (+epilogue). A:[M,lda] bf16, B:[N,ldb] bf16 (row-major).
// 128x128 tile, BK=32, 256 threads (4 waves 2x2), mfma_f32_16x16x32_bf16.
// Staging: explicit global int4 load -> ds_write_b128 (NO global_load_lds).
// Batched via blockIdx.z (strides sA/sB). K must be a multiple of 32.
// MODE 0: C bf16 [m*768+n] = (val + raw1[r1off+n]) * scale      (q/k proj)
// MODE 1: C bf16 vT[((m/197)*768+n)*224 + m%197] = val+raw1[r1off+n]
// MODE 2: C f32 scores[bz*38809 + m*197 + n] = val
// MODE 3: C bf16 aoT[(bz*768+n)*2688 + hoff + m] = val
// MODE 4: C bf16 outS[(row0+bz*197+m)*768+n] = val + bmap(raw1)[m] + x(raw2)[gi]
// MODE 5: C bf16 [m*3072+n] = gelu(val + raw1[n])               (mlp1)
// MODE 6: d_out[(row0+m)*768+n] = val + raw1[n] + bf16 raw2[m*768+n]; dtype=flag
// ---------------------------------------------------------------------------
template <int MODE>
__global__ __launch_bounds__(256) void mgemm(
    const bf16* __restrict__ Aall, const bf16* __restrict__ Ball,
    void* __restrict__ C,
    const void* __restrict__ raw1, long r1off, const void* __restrict__ raw2,
    int M, int N, int K, int lda, int ldb, long sA, long sB,
    int hoff, long row0, float scale, const int* __restrict__ flag)
{
    __shared__ short As[4096];   // 128 rows x 32 k (bf16)
    __shared__ short Bs[4096];

    const int tid  = threadIdx.x;
    const int wave = tid >> 6, lane = tid & 63;
    const int wy = wave >> 1, wx = wave & 1;
    const int lane16 = lane & 15, kg = lane >> 4;
    const int m0 = blockIdx.y * 128, n0 = blockIdx.x * 128;
    const int bz = blockIdx.z;

    const bf16* A = Aall + (long)bz * sA;
    const bf16* B = Ball + (long)bz * sB;

    // chunk c (0..511): row = c>>2, k-chunk = (c&3)*8 ; LDS short offset = c*8
    const int c0 = tid, c1 = tid + 256;
    const long rA0 = min(m0 + (c0 >> 2), M - 1);
    const long rA1 = min(m0 + (c1 >> 2), M - 1);
    const long rB0 = min(n0 + (c0 >> 2), N - 1);
    const long rB1 = min(n0 + (c1 >> 2), N - 1);
    const int k0c = (c0 & 3) * 8, k1c = (c1 & 3) * 8;

    floatx4 acc[4][4];
#pragma unroll
    for (int i = 0; i < 4; i++)
#pragma unroll
        for (int j = 0; j < 4; j++) acc[i][j] = (floatx4){0.f, 0.f, 0.f, 0.f};

    const int aoff = (wy * 64 + lane16) * 32 + kg * 8;  // shorts
    const int boff = (wx * 64 + lane16) * 32 + kg * 8;

    for (int kt = 0; kt < K; kt += 32) {
        const int4 av0 = *(const int4*)(A + rA0 * lda + kt + k0c);
        const int4 av1 = *(const int4*)(A + rA1 * lda + kt + k1c);
        const int4 bv0 = *(const int4*)(B + rB0 * ldb + kt + k0c);
        const int4 bv1 = *(const int4*)(B + rB1 * ldb + kt + k1c);
        __syncthreads();                      // previous iteration's reads done
        *(int4*)(As + c0 * 8) = av0;
        *(int4*)(As + c1 * 8) = av1;
        *(int4*)(Bs + c0 * 8) = bv0;
        *(int4*)(Bs + c1 * 8) = bv1;
        __syncthreads();                      // writes visible
        bfx8 a[4], b[4];
#pragma unroll
        for (int i = 0; i < 4; i++) a[i] = *(const bfx8*)(As + aoff + i * 512);
#pragma unroll
        for (int j = 0; j < 4; j++) b[j] = *(const bfx8*)(Bs + boff + j * 512);
#pragma unroll
        for (int i = 0; i < 4; i++)
#pragma unroll
            for (int j = 0; j < 4; j++)
                acc[i][j] = __builtin_amdgcn_mfma_f32_16x16x32_bf16(a[i], b[j], acc[i][j], 0, 0, 0);
    }

    // epilogue. C/D: col = lane&15, row = (lane>>4)*4 + r  [m89/m91 verified]
    const int fl = *flag;
    const int mbase = m0 + wy * 64 + kg * 4;
    const int nbase = n0 + wx * 64 + lane16;
#pragma unroll
    for (int i = 0; i < 4; i++) {
#pragma unroll
        for (int j = 0; j < 4; j++) {
            const int n = nbase + j * 16;
#pragma unroll
            for (int r = 0; r < 4; r++) {
                const int m = mbase + i * 16 + r;
                if (m >= M || n >= N) continue;
                float val = acc[i][j][r];
                if constexpr (MODE == 0) {
                    ((bf16*)C)[(long)m * 768 + n] =
                        __float2bfloat16((val + rd(raw1, r1off + n, fl)) * scale);
                } else if constexpr (MODE == 1) {
                    int b_ = m / 197, t = m - b_ * 197;
                    ((bf16*)C)[((long)b_ * 768 + n) * 224 + t] =
                        __float2bfloat16(val + rd(raw1, r1off + n, fl));
                } else if constexpr (MODE == 2) {
                    ((float*)C)[(long)bz * 38809 + (long)m * 197 + n] = val;
                } else if constexpr (MODE == 3) {
                    ((bf16*)C)[((long)bz * 768 + n) * 2688 + hoff + m] = __float2bfloat16(val);
                } else if constexpr (MODE == 4) {
                    long gi = (row0 + (long)bz * 197 + m) * 768 + n;
                    ((bf16*)C)[gi] =
                        __float2bfloat16(val + rd(raw1, m, fl) + rd(raw2, gi, fl));
                } else if constexpr (MODE == 5) {
                    float xv = val + rd(raw1, r1off + n, fl);
                    xv = 0.5f * xv * (1.f + erff(xv * 0.70710678f));
                    ((bf16*)C)[(long)m * 3072 + n] = __float2bfloat16(xv);
                } else if constexpr (MODE == 6) {
                    float res = val + rd(raw1, r1off + n, fl)
                              + b2f(((const bf16*)raw2)[(long)m * 768 + n]);
                    long ad = (row0 + m) * 768 + n;
                    if (fl) ((float*)C)[ad] = res;
                    else    ((bf16*)C)[ad] = __float2bfloat16(res);
                }
            }
        }
    }
}

extern "C" void kernel_launch(void* const* d_in, const int* in_sizes, int n_in,
                              void* d_out, int out_size, void* d_ws, size_t ws_size,
                              hipStream_t stream)
{
    const void* x    = d_in[0];
    const void* ln1g = d_in[1];
    const void* ln1b = d_in[2];
    const void* Wq   = d_in[3];
    const void* bq   = d_in[4];
    const void* Wk   = d_in[5];
    const void* bk   = d_in[6];
    const void* Wv   = d_in[7];
    const void* bv   = d_in[8];
    const void* Wmap = d_in[9];
    const void* bmap = d_in[10];
    const void* ln2g = d_in[11];
    const void* ln2b = d_in[12];
    const void* W1   = d_in[13];
    const void* b1   = d_in[14];
    const void* W2   = d_in[15];
    const void* b2   = d_in[16];
    (void)in_sizes; (void)n_in; (void)out_size;

    auto al   = [](size_t v) { return (v + 255) & ~(size_t)255; };
    auto cdiv = [](long a, long b) { return (int)((a + b - 1) / b); };

    // ---- reserved (lives across both phases) ----
    char* W = (char*)d_ws;
    size_t o = 0;
    auto take = [&](size_t bytes) -> char* { char* p = W + o; o += al(bytes); return p; };
    int*  flag  = (int*)take(256);
    bf16* outS  = (bf16*)take(6304ull * 768 * 2);    // x + msa (bf16)
    bf16* wmpad = (bf16*)take(197ull * 2688 * 2);    // Wmap padded per-head to 224
    const size_t reservedB = o;
    char* arena = W + reservedB;

    // ---- adaptive chunk sizes ----
    auto p1need = [&](int BC) -> size_t {
        size_t b = (size_t)BC;
        return reservedB + al(3ull * 589824 * 2)     // Wqkvb
             + 3 * al(b * 197 * 768 * 2)             // hlnC, qC, kC
             + al(b * 768 * 224 * 2)                 // vTC
             + al(b * 38809 * 4)                     // scoresC
             + al(b * 197 * 224 * 2)                 // attnC
             + al(b * 768 * 2688 * 2);               // aoTg
    };
    int BC = 1;
    { const int ch[6] = {32, 16, 8, 4, 2, 1};
      for (int i = 0; i < 6; i++) if (p1need(ch[i]) <= ws_size) { BC = ch[i]; break; } }

    auto p2need = [&](int MC) -> size_t {
        return reservedB + 2 * al(2359296ull * 2)
             + al((size_t)MC * 768 * 2) + al((size_t)MC * 3072 * 2);
    };
    int MC = 197;
    { const int ch[6] = {6304, 3152, 1576, 788, 394, 197};
      for (int i = 0; i < 6; i++) if (p2need(ch[i]) <= ws_size) { MC = ch[i]; break; } }

    // phase-1 buffers
    size_t po = 0;
    auto ptake = [&](size_t bytes) -> char* { char* p = arena + po; po += al(bytes); return p; };
    bf16*  Wqkvb   = (bf16*)ptake(3ull * 589824 * 2);
    bf16*  hlnC    = (bf16*)ptake((size_t)BC * 197 * 768 * 2);
    bf16*  qC      = (bf16*)ptake((size_t)BC * 197 * 768 * 2);
    bf16*  kC      = (bf16*)ptake((size_t)BC * 197 * 768 * 2);
    bf16*  vTC     = (bf16*)ptake((size_t)BC * 768 * 224 * 2);
    float* scoresC = (float*)ptake((size_t)BC * 38809 * 4);
    bf16*  attnC   = (bf16*)ptake((size_t)BC * 197 * 224 * 2);
    bf16*  aoTg    = (bf16*)ptake((size_t)BC * 768 * 2688 * 2);
    // phase-2 buffers (alias arena; phase-1 data dead by then)
    size_t qo = 0;
    auto qtake = [&](size_t bytes) -> char* { char* p = arena + qo; qo += al(bytes); return p; };
    bf16* W1b = (bf16*)qtake(2359296ull * 2);
    bf16* W2b = (bf16*)qtake(2359296ull * 2);
    bf16* h2C = (bf16*)qtake((size_t)MC * 768 * 2);
    bf16* gC  = (bf16*)qtake((size_t)MC * 3072 * 2);

    detect_dtype<<<1, 256, 0, stream>>>((const unsigned short*)x, flag);
    pad_wmap<<<cdiv(197L * 2688, 256), 256, 0, stream>>>(Wmap, wmpad, flag);

    const int Mr = BC * 197;
    const int gy = cdiv(Mr, 128);
    for (int c0 = 0; c0 < 32; c0 += BC) {
        const long row0 = (long)c0 * 197;
        ln_bf<<<Mr, 256, 0, stream>>>(x, 1, ln1g, ln1b, hlnC, row0, flag);
        for (int h = 0; h < 12; h++) {
            cvt3<<<2304, 256, 0, stream>>>(Wq, Wk, Wv, (long)h * 589824, Wqkvb, flag);
            const bf16* Wqb = Wqkvb;
            const bf16* Wkb = Wqkvb + 589824;
            const bf16* Wvb = Wqkvb + 2 * 589824;
            mgemm<0><<<dim3(6, gy, 1), 256, 0, stream>>>(hlnC, Wqb, qC, bq, (long)h * 768,
                nullptr, Mr, 768, 768, 768, 768, 0, 0, 0, 0, 1.0f / 14.0f, flag);
            mgemm<0><<<dim3(6, gy, 1), 256, 0, stream>>>(hlnC, Wkb, kC, bk, (long)h * 768,
                nullptr, Mr, 768, 768, 768, 768, 0, 0, 0, 0, 1.0f, flag);
            mgemm<1><<<dim3(6, gy, 1), 256, 0, stream>>>(hlnC, Wvb, vTC, bv, (long)h * 768,
                nullptr, Mr, 768, 768, 768, 768, 0, 0, 0, 0, 1.0f, flag);
            // scores[b] = q[b] @ k[b]^T : M=N=197, K=768
            mgemm<2><<<dim3(2, 2, BC), 256, 0, stream>>>(qC, kC, scoresC, nullptr, 0,
                nullptr, 197, 197, 768, 768, 768, 197L * 768, 197L * 768, 0, 0, 1.0f, flag);
            softmax_rows<<<cdiv((long)Mr, 4), 256, 0, stream>>>(scoresC, attnC, Mr);
            // ao[b] = attn[b] @ vT[b]^T : M=197, N=768, K=224 -> aoTg slice h
            mgemm<3><<<dim3(6, 2, BC), 256, 0, stream>>>(attnC, vTC, aoTg, nullptr, 0,
                nullptr, 197, 768, 224, 224, 224, 197L * 224, 768L * 224, h * 224, 0, 1.0f, flag);
        }
        // outS = Wmap_pad @ aoTg[b]^T + bmap + x : M=197, N=768, K=2688
        mgemm<4><<<dim3(6, 2, BC), 256, 0, stream>>>(wmpad, aoTg, outS, bmap, 0,
            x, 197, 768, 2688, 2688, 2688, 0, 768L * 2688, 0, row0, 1.0f, flag);
    }

    // ---- MLP phase ----
    cvt_b16<<<cdiv(2359296, 256), 256, 0, stream>>>(W1, W1b, 2359296, flag);
    cvt_b16<<<cdiv(2359296, 256), 256, 0, stream>>>(W2, W2b, 2359296, flag);
    for (int r0 = 0; r0 < 6304; r0 += MC) {
        const int gy2 = cdiv(MC, 128);
        ln_bf<<<MC, 256, 0, stream>>>(outS, 0, ln2g, ln2b, h2C, r0, flag);
        mgemm<5><<<dim3(24, gy2, 1), 256, 0, stream>>>(h2C, W1b, gC, b1, 0, nullptr,
            MC, 3072, 768, 768, 768, 0, 0, 0, 0, 1.0f, flag);
        mgemm<6><<<dim3(6, gy2, 1), 256, 0, stream>>>(gC, W2b, d_out, b2, 0, h2C,
            MC, 768, 3072, 3072, 3072, 0, 0, 0, r0, 1.0f, flag);
    }
}